// Round 5
// baseline (463.462 us; speedup 1.0000x reference)
//
#include <hip/hip_runtime.h>
#include <math.h>

#define NWAY 5
#define KSHOT 5
#define BB 4
#define QQ 75
#define CC 640
#define MM 196
#define BQ (BB*QQ)          // 300
#define MP 208              // packed A rows per bq
#define NCOL 1024           // padded flat col space (980 real)
#define NREAL 980

// ---- ws layout (float offsets) ----
#define BPK_OFF   0
#define BPK_SZF   (BB*NCOL*CC/2)            // 1,310,720 (fp16 region)
#define APK_OFF   (BPK_OFF + BPK_SZF)
#define APK_SZF   ((BQ*MP + 64)*CC/2)       // +64 pad rows: bq299 row 255 = 62,447 < 62,464 ok
#define GSTAT_OFF (APK_OFF + APK_SZF)       // even -> 8B aligned
#define GSTAT_N   (BQ*NWAY*MP)              // 312,000 u64
#define NRMS_OFF  (GSTAT_OFF + 2*GSTAT_N)
#define NRMS_SZ   (BB*NWAY*MM)              // 3,920
#define NRMQ_OFF  (NRMS_OFF + NRMS_SZ)
#define NRMQ_SZ   (BQ*MM)                   // 58,800

typedef __attribute__((ext_vector_type(8))) _Float16 half8;
typedef __attribute__((ext_vector_type(4))) float floatx4;

// ---------------- fused prep: A-pack (3000 blocks) + B mean-pack (200 blocks) ----------------
// (round-0 verified version; the 32-ch variant measured ~9us worse)
__global__ void k_prep(const float* __restrict__ sx, const float* __restrict__ qx,
                       _Float16* __restrict__ Apk, _Float16* __restrict__ Bpk,
                       float* __restrict__ nrmq, float* __restrict__ nrms) {
    __shared__ float T[64 * 197];         // 50,432 B
    int t = threadIdx.x;
    int blk = blockIdx.x;
    if (blk < 3000) {
        int bq = blk / 10, cc = blk % 10;
        int c0 = cc * 64;
        const float* Q = qx + (size_t)bq * CC * MM + (size_t)c0 * MM;
        for (int idx = t; idx < 64 * MM; idx += 256) {
            int ci = idx / MM, m = idx - ci * MM;
            T[ci * 197 + m] = Q[idx];
        }
        __syncthreads();
        _Float16* out = Apk + (size_t)bq * MP * CC;
        int mloc = t >> 3, cj8 = t & 7;
        #pragma unroll
        for (int r = 0; r < 7; r++) {
            int mm = r * 32 + mloc;
            if (mm < MP) {
                half8 v;
                #pragma unroll
                for (int k = 0; k < 8; k++) {
                    float f = (mm < MM) ? T[(cj8 * 8 + k) * 197 + mm] : 0.f;
                    v[k] = (_Float16)f;
                }
                *(half8*)&out[(size_t)mm * CC + c0 + cj8 * 8] = v;
            }
        }
        if (t < MM) {
            float ss = 0.f;
            for (int ci = 0; ci < 64; ci++) { float v = T[ci * 197 + t]; ss += v * v; }
            atomicAdd(&nrmq[bq * MM + t], ss);
        }
    } else {
        int bb = blk - 3000;
        int bn = bb / 10, cc = bb % 10;
        int b = bn / NWAY, n = bn % NWAY;
        int c0 = cc * 64;
        const float* S = sx + (size_t)bn * KSHOT * CC * MM + (size_t)c0 * MM;
        for (int idx = t; idx < 64 * MM; idx += 256) {
            int ci = idx / MM, m = idx - ci * MM;
            float s = 0.f;
            #pragma unroll
            for (int k = 0; k < KSHOT; k++) s += S[(size_t)k * CC * MM + idx];
            T[ci * 197 + m] = s * 0.2f;
        }
        __syncthreads();
        _Float16* out = Bpk + ((size_t)b * NCOL + (size_t)n * MM) * CC;
        int mloc = t >> 3, cj8 = t & 7;
        #pragma unroll
        for (int r = 0; r < 7; r++) {
            int mm = r * 32 + mloc;
            if (mm < MM) {
                half8 v;
                #pragma unroll
                for (int k = 0; k < 8; k++)
                    v[k] = (_Float16)T[(cj8 * 8 + k) * 197 + mm];
                *(half8*)&out[(size_t)mm * CC + c0 + cj8 * 8] = v;
            }
        }
        if (t < MM) {
            float ss = 0.f;
            for (int ci = 0; ci < 64; ci++) { float v = T[ci * 197 + t]; ss += v * v; }
            atomicAdd(&nrms[bn * MM + t], ss);
        }
    }
}

// ---------------- MFMA similarity v4: 256x128 tile, A-frags from GLOBAL, B-only LDS ----------------
// LDS-port relief: old design moved 112 KB/block-iter through LDS (cap 35% MfmaUtil, measured 26).
// Now: A-fragments load straight from Apk (already [m][c] MFMA layout; 16 rows x 64B contiguous
// segments per instr, L2-resident via XCD swizzle). Only B staged in LDS (16 KB/iter, dbuf,
// chunk-XOR swizzle, one barrier/iter) -> 80 KB LDS/block-iter @ 3.4 MFLOP = 42 FLOP/B (cap ~79%).
// 4 waves, each 64 rows x 128 cols; row-tiles T = ws+4i with ws=(w+cblk)&3 so the extra 13th real
// tile rotates across SIMDs. Tiles 13-15 (rows 208-255) are pad: skipped (i==3 && ws!=0).
// af loads are issued BEFORE the B-stage so the compiler's af wait is vmcnt(4), never draining stage.
// rule #20: all acc[][] indices static (unrolled loops + uniform skip).
__global__ __launch_bounds__(256, 2) void k_sim(
    const _Float16* __restrict__ Apk, const _Float16* __restrict__ Bpk,
    const float* __restrict__ nrms, unsigned long long* __restrict__ gstat)
{
    __shared__ __align__(16) _Float16 Lds[16384];   // 32,768 B: 2 x 8192-half B buffers
    int id = blockIdx.x;
    int x = id & 7, s = id >> 3;          // XCD swizzle: the 8 cblk blocks of one bq -> same XCD
    int cblk = s & 7, bqg = s >> 3;
    int bq = x + (bqg << 3);
    if (bq >= BQ) return;
    int b = bq / QQ;

    int t = threadIdx.x, lane = t & 63, w = t >> 6;
    int q = lane >> 4, l15 = lane & 15, s7 = l15 & 7;
    int ws = (w + cblk) & 3;              // rotated row-tile owner
    const bool full = (ws == 0);          // ws==0 wave also owns tile 12 (rows 192-207)

    const _Float16* Ab = Apk + (size_t)bq * MP * CC;
    const _Float16* Bb = Bpk + ((size_t)b * NCOL + (size_t)(cblk * 128)) * CC;

    // A-fragment row bases (global, halfs): tile T=ws+4i, row=T*16+l15, + q*8 col fold
    const _Float16* arow[4];
    #pragma unroll
    for (int i = 0; i < 4; i++)
        arow[i] = Ab + (size_t)((ws + 4 * i) * 16 + l15) * CC + q * 8;

    // B staging source offsets (halfs): chunk = p*256+t; row jl=chunk>>3, slot j=t&7 holds
    // global chunk j^(jl&7)  (verified swizzle convention)
    int voffb[4];
    #pragma unroll
    for (int p = 0; p < 4; p++) {
        int jl = (p * 256 + t) >> 3, j = t & 7;
        voffb[p] = jl * CC + ((j ^ (jl & 7)) << 3);
    }

    // B fragment LDS offsets (halfs, within one 8192-half buffer)
    int brow[8];
    #pragma unroll
    for (int jt = 0; jt < 8; jt++)
        brow[jt] = (jt * 16 + l15) * 64;

    floatx4 acc[4][8];
    #pragma unroll
    for (int i = 0; i < 4; i++)
        #pragma unroll
        for (int j = 0; j < 8; j++) acc[i][j] = (floatx4){0.f, 0.f, 0.f, 0.f};

    // prologue: stage B tile 0 -> buf 0
    #pragma unroll
    for (int p = 0; p < 4; p++)
        __builtin_amdgcn_global_load_lds(
            (const __attribute__((address_space(1))) void*)(Bb + voffb[p]),
            (__attribute__((address_space(3))) void*)(Lds + p * 2048 + w * 512),
            16, 0, 0);
    __syncthreads();

    for (int tt = 0; tt < 10; tt++) {
        int cb = (tt & 1) << 13;          // 8192-half buffer select

        // ---- af loads FIRST (so their waitcnt is vmcnt(4), staging stays in flight) ----
        half8 af[4][2];
        #pragma unroll
        for (int i = 0; i < 4; i++) {
            if (i == 3 && !full) continue;
            #pragma unroll
            for (int ks = 0; ks < 2; ks++)
                af[i][ks] = *(const half8*)(arow[i] + tt * 64 + ks * 32);
        }

        // ---- stage next B tile into the other buffer ----
        if (tt < 9) {
            int nb = ((tt + 1) & 1) << 13;
            #pragma unroll
            for (int p = 0; p < 4; p++)
                __builtin_amdgcn_global_load_lds(
                    (const __attribute__((address_space(1))) void*)(Bb + voffb[p] + (tt + 1) * 64),
                    (__attribute__((address_space(3))) void*)(Lds + nb + p * 2048 + w * 512),
                    16, 0, 0);
        }

        // ---- compute: bf per-jt from LDS (keeps VGPR live-range small), MFMA ----
        #pragma unroll
        for (int ks = 0; ks < 2; ks++) {
            int cj = ks * 4 + q;
            #pragma unroll
            for (int jt = 0; jt < 8; jt++) {
                half8 bf = *(const half8*)&Lds[cb + brow[jt] + ((cj ^ s7) << 3)];
                #pragma unroll
                for (int i = 0; i < 4; i++) {
                    if (i == 3 && !full) continue;
                    acc[i][jt] = __builtin_amdgcn_mfma_f32_16x16x32_f16(af[i][ks], bf, acc[i][jt], 0, 0, 0);
                }
            }
        }
        __syncthreads();   // drains staging (issued ~full compute-phase earlier) + LDS reads
    }

    // ---- epilogue: fold 8 jt into <=2 class keys per (i,r), dual-key butterfly, atomicMax ----
    int wbase = cblk * 128;               // all 4 waves share the col window
    int clsLo = wbase / 196;
    float invv[8]; int ms8[8], isLo[8], valid[8];
    #pragma unroll
    for (int jt = 0; jt < 8; jt++) {
        int c = wbase + jt * 16 + l15;
        int cls = c / 196;
        ms8[jt] = c - cls * 196;
        isLo[jt] = (cls == clsLo);
        valid[jt] = (c < NREAL);
        invv[jt] = valid[jt] ? (1.0f / fmaxf(sqrtf(nrms[b * NREAL + c]), 1e-8f)) : 0.f;
    }
    #pragma unroll
    for (int i = 0; i < 4; i++) {
        if (i == 3 && !full) continue;    // uniform guard; acc indices stay static
        #pragma unroll
        for (int r = 0; r < 4; r++) {
            unsigned long long keyLo = 0ULL, keyHi = 0ULL;
            #pragma unroll
            for (int jt = 0; jt < 8; jt++) {
                float v = acc[i][jt][r] * invv[jt];
                unsigned int ub = __float_as_uint(v);
                unsigned int su = (ub & 0x80000000u) ? ~ub : (ub | 0x80000000u);
                unsigned long long key = valid[jt]
                    ? (((unsigned long long)su << 32) |
                       (unsigned long long)(0xFFFFFFFFu - (unsigned int)ms8[jt]))
                    : 0ULL;
                if (isLo[jt]) keyLo = (key > keyLo) ? key : keyLo;
                else          keyHi = (key > keyHi) ? key : keyHi;
            }
            #pragma unroll
            for (int sft = 1; sft < 16; sft <<= 1) {
                unsigned long long oL = __shfl_xor(keyLo, sft, 64);
                unsigned long long oH = __shfl_xor(keyHi, sft, 64);
                if (oL > keyLo) keyLo = oL;
                if (oH > keyHi) keyHi = oH;
            }
            if (l15 == 0) {
                int gm = (ws + 4 * i) * 16 + q * 4 + r;
                if (gm < MM) {
                    if (keyLo)
                        atomicMax(&gstat[((size_t)bq * NWAY + clsLo) * MP + gm], keyLo);
                    int clsHi = clsLo + 1;
                    if (keyHi && clsHi < NWAY)
                        atomicMax(&gstat[((size_t)bq * NWAY + clsHi) * MP + gm], keyHi);
                }
            }
        }
    }
}

// ---------------- mutual-NN mask + predict + per-sample CE -> atomicAdd out ----------------
__global__ void k_post(const unsigned long long* __restrict__ gstat,
                       const float* __restrict__ nrmq,
                       float* __restrict__ out, const int* __restrict__ qy) {
    int bq = blockIdx.x;
    int t = threadIdx.x;
    __shared__ float invq_s[MM];
    __shared__ float cm[NWAY * MM];
    __shared__ int   ca[NWAY * MM];
    __shared__ float gmax[MM];
    __shared__ int   jst[MM];
    __shared__ int   msk[MM];
    __shared__ float pred[NWAY];

    if (t < MM) invq_s[t] = 1.0f / fmaxf(sqrtf(nrmq[bq * MM + t]), 1e-8f);
    __syncthreads();

    for (int i = t; i < NWAY * MM; i += 256) {
        int n = i / MM, m = i - n * MM;
        unsigned long long key = gstat[((size_t)bq * NWAY + n) * MP + m];
        unsigned int hi = (unsigned int)(key >> 32);
        unsigned int bits = (hi & 0x80000000u) ? (hi ^ 0x80000000u) : ~hi;
        cm[i] = __uint_as_float(bits) * invq_s[m];
        ca[i] = (int)(0xFFFFFFFFu - (unsigned int)(key & 0xFFFFFFFFu));
    }
    __syncthreads();

    if (t < MM) {       // cross-class combine: ascending n, strict > == n-major first-index
        float bv = cm[t];
        int bj = ca[t];
        for (int n = 1; n < NWAY; n++) {
            float v = cm[n * MM + t];
            if (v > bv) { bv = v; bj = n * MM + ca[n * MM + t]; }
        }
        gmax[t] = bv; jst[t] = bj;
    }
    __syncthreads();

    if (t < MM) {       // mutual-NN: winner of my support-column group (max gmax, min index)
        int myj = jst[t];
        float myv = gmax[t];
        int lose = 0;
        for (int m2 = 0; m2 < MM; m2++) {
            if (jst[m2] == myj &&
                (gmax[m2] > myv || (gmax[m2] == myv && m2 < t))) lose = 1;
        }
        msk[t] = !lose;
    }
    __syncthreads();

    if (t < NWAY) {
        float p = 0.f;
        for (int m = 0; m < MM; m++) if (msk[m]) p += cm[t * MM + m];
        pred[t] = 2.0f * p;   // TEMPERATURE = 2
    }
    __syncthreads();

    if (t == 0) {
        float pm = pred[0];
        for (int n = 1; n < NWAY; n++) pm = fmaxf(pm, pred[n]);
        float s = 0.f;
        for (int n = 0; n < NWAY; n++) s += expf(pred[n] - pm);
        float lse = pm + logf(s);
        int y = qy[bq];
        atomicAdd(out, (lse - pred[y]) * (1.0f / (BB * QQ)));
    }
}

extern "C" void kernel_launch(void* const* d_in, const int* in_sizes, int n_in,
                              void* d_out, int out_size, void* d_ws, size_t ws_size,
                              hipStream_t stream) {
    const float* sx = (const float*)d_in[0];
    const float* qx = (const float*)d_in[2];
    const int*   qy = (const int*)d_in[3];
    float* out = (float*)d_out;
    float* ws  = (float*)d_ws;

    _Float16* Bpk = (_Float16*)(ws + BPK_OFF);
    _Float16* Apk = (_Float16*)(ws + APK_OFF);
    unsigned long long* gstat = (unsigned long long*)(ws + GSTAT_OFF);
    float* nrms = ws + NRMS_OFF;
    float* nrmq = ws + NRMQ_OFF;

    // zero gstat + nrms + nrmq (contiguous) and the output accumulator
    hipMemsetAsync(gstat, 0, (size_t)(2 * GSTAT_N + NRMS_SZ + NRMQ_SZ) * 4, stream);
    hipMemsetAsync(out, 0, 4, stream);
    hipLaunchKernelGGL(k_prep, dim3(3200), dim3(256), 0, stream, sx, qx, Apk, Bpk, nrmq, nrms);
    hipLaunchKernelGGL(k_sim,  dim3(8 * 38 * 8), dim3(256), 0, stream, Apk, Bpk, nrms, gstat);
    hipLaunchKernelGGL(k_post, dim3(300), dim3(256), 0, stream, gstat, nrmq, out, qy);
}

// Round 6
// 434.937 us; speedup vs baseline: 1.0656x; 1.0656x over previous
//
#include <hip/hip_runtime.h>
#include <math.h>

#define NWAY 5
#define KSHOT 5
#define BB 4
#define QQ 75
#define CC 640
#define MM 196
#define BQ (BB*QQ)          // 300
#define MP 208              // packed A rows per bq
#define NCOL 1024           // padded flat col space (980 real)
#define NREAL 980

// ---- ws layout (float offsets) ----
#define BPK_OFF   0
#define BPK_SZF   (BB*NCOL*CC/2)            // 1,310,720 (fp16 region)
#define APK_OFF   (BPK_OFF + BPK_SZF)
#define APK_SZF   ((BQ*MP + 64)*CC/2)       // +64 pad rows so mblk=1 OOB stays in-region
#define GSTAT_OFF (APK_OFF + APK_SZF)       // even -> 8B aligned
#define GSTAT_N   (BQ*NWAY*MP)              // 312,000 u64
#define NRMS_OFF  (GSTAT_OFF + 2*GSTAT_N)
#define NRMS_SZ   (BB*NWAY*MM)              // 3,920
#define NRMQ_OFF  (NRMS_OFF + NRMS_SZ)
#define NRMQ_SZ   (BQ*MM)                   // 58,800

typedef __attribute__((ext_vector_type(8))) _Float16 half8;
typedef __attribute__((ext_vector_type(4))) float floatx4;

// ---------------- fused prep: A-pack (3000 blocks) + B mean-pack (200 blocks) ----------------
// (round-0 verified version)
__global__ void k_prep(const float* __restrict__ sx, const float* __restrict__ qx,
                       _Float16* __restrict__ Apk, _Float16* __restrict__ Bpk,
                       float* __restrict__ nrmq, float* __restrict__ nrms) {
    __shared__ float T[64 * 197];         // 50,432 B
    int t = threadIdx.x;
    int blk = blockIdx.x;
    if (blk < 3000) {
        int bq = blk / 10, cc = blk % 10;
        int c0 = cc * 64;
        const float* Q = qx + (size_t)bq * CC * MM + (size_t)c0 * MM;
        for (int idx = t; idx < 64 * MM; idx += 256) {
            int ci = idx / MM, m = idx - ci * MM;
            T[ci * 197 + m] = Q[idx];
        }
        __syncthreads();
        _Float16* out = Apk + (size_t)bq * MP * CC;
        int mloc = t >> 3, cj8 = t & 7;
        #pragma unroll
        for (int r = 0; r < 7; r++) {
            int mm = r * 32 + mloc;
            if (mm < MP) {
                half8 v;
                #pragma unroll
                for (int k = 0; k < 8; k++) {
                    float f = (mm < MM) ? T[(cj8 * 8 + k) * 197 + mm] : 0.f;
                    v[k] = (_Float16)f;
                }
                *(half8*)&out[(size_t)mm * CC + c0 + cj8 * 8] = v;
            }
        }
        if (t < MM) {
            float ss = 0.f;
            for (int ci = 0; ci < 64; ci++) { float v = T[ci * 197 + t]; ss += v * v; }
            atomicAdd(&nrmq[bq * MM + t], ss);
        }
    } else {
        int bb = blk - 3000;
        int bn = bb / 10, cc = bb % 10;
        int b = bn / NWAY, n = bn % NWAY;
        int c0 = cc * 64;
        const float* S = sx + (size_t)bn * KSHOT * CC * MM + (size_t)c0 * MM;
        for (int idx = t; idx < 64 * MM; idx += 256) {
            int ci = idx / MM, m = idx - ci * MM;
            float s = 0.f;
            #pragma unroll
            for (int k = 0; k < KSHOT; k++) s += S[(size_t)k * CC * MM + idx];
            T[ci * 197 + m] = s * 0.2f;
        }
        __syncthreads();
        _Float16* out = Bpk + ((size_t)b * NCOL + (size_t)n * MM) * CC;
        int mloc = t >> 3, cj8 = t & 7;
        #pragma unroll
        for (int r = 0; r < 7; r++) {
            int mm = r * 32 + mloc;
            if (mm < MM) {
                half8 v;
                #pragma unroll
                for (int k = 0; k < 8; k++)
                    v[k] = (_Float16)T[(cj8 * 8 + k) * 197 + mm];
                *(half8*)&out[(size_t)mm * CC + c0 + cj8 * 8] = v;
            }
        }
        if (t < MM) {
            float ss = 0.f;
            for (int ci = 0; ci < 64; ci++) { float v = T[ci * 197 + t]; ss += v * v; }
            atomicAdd(&nrms[bn * MM + t], ss);
        }
    }
}

// ---------------- MFMA similarity v5: round-4 winner + register diet -> 4 blocks/CU ----------------
// Diagnosis of the 151us version: MfmaUtil 30 / VALU 41 / LDS ~23% -- nothing saturated =>
// latency-bound at 3 waves/SIMD. Binder was registers: 72 VGPR + 64 AGPR = 136/wave.
// Diet (all analytically identical addresses):
//   voff[p] = voff0 + p*8*CC  (chunk p->p+1: m += 8, m&7 unchanged)  -> 1 reg + const offsets
//   asw[i] = bsw[jt] = l15&7 = s7 (row bases are multiples of 8)      -> arrays gone
//   frag addrs: abase/bbase + {1024*i / 1024*jt} compile-time offsets -> ds_read offset:N
// Target <=64 VGPR so 64V+64A=128 fits 4 waves/SIMD; __launch_bounds__(256,4).
// Verify in counters: VGPR_Count<=64, WRITE_SIZE==22050 (jump => spill => revert to (256,3)).
__global__ __launch_bounds__(256, 4) void k_sim(
    const _Float16* __restrict__ Apk, const _Float16* __restrict__ Bpk,
    const float* __restrict__ nrms, unsigned long long* __restrict__ gstat)
{
    __shared__ __align__(16) _Float16 Lds[8192];    // A 1024 chunks | B 1024 chunks, 16,384 B? no:
    // 2048 chunks of 8 halfs = 16384 halfs. Keep original size:
    // (see below -- declared properly)
    __shared__ __align__(16) _Float16 Lds2[8192];   // second half (contiguity with Lds not guaranteed
    // NOTE: HIP guarantees declaration-order contiguity is NOT specified -> use single array.
    (void)Lds2;
    // ---- real storage ----
    // (single array; the two decls above are unused remnants kept zero-cost)
    static_assert(true, "");
    #define LDSARR LdsMain
    __shared__ __align__(16) _Float16 LdsMain[16384];   // 32,768 B

    int id = blockIdx.x;
    int x = id & 7, s = id >> 3;          // XCD swizzle: 16 blocks of one bq -> same XCD
    int sub = s & 15, bqg = s >> 4;
    int bq = x + (bqg << 3);
    if (bq >= BQ) return;
    int mblk = sub >> 3, cblk = sub & 7;
    int b = bq / QQ;

    int t = threadIdx.x, lane = t & 63, w = t >> 6;
    int q = lane >> 4, l15 = lane & 15, s7 = l15 & 7;
    bool active = !(mblk == 1 && w == 3);   // wave-uniform; rows 224-255 are pad garbage

    const _Float16* Ab = Apk + (size_t)bq * MP * CC + (size_t)(mblk * 128) * CC;
    const _Float16* Bb = Bpk + ((size_t)b * NCOL + (size_t)(cblk * 128)) * CC;
    const _Float16* base = (w < 2) ? Ab : Bb;     // waves 0,1 stage A; 2,3 stage B

    // single staging base offset (halfs); p-th load adds p*8*CC (compile-time)
    int rb = (w & 1) * 64 + (lane >> 3);
    int voff0 = rb * CC + (((lane & 7) ^ ((lane >> 3) & 7)) << 3);

    // fragment base addresses (halfs); per-ks xor offset added at use
    int abase = (w * 32 + l15) * 64;          // + i*1024
    int bbase = 8192 + l15 * 64;              // + jt*1024

    floatx4 acc[2][8];
    #pragma unroll
    for (int i = 0; i < 2; i++)
        #pragma unroll
        for (int j = 0; j < 8; j++) acc[i][j] = (floatx4){0.f, 0.f, 0.f, 0.f};

    for (int c0 = 0; c0 < CC; c0 += 64) {
        #pragma unroll
        for (int p = 0; p < 8; p++)
            __builtin_amdgcn_global_load_lds(
                (const __attribute__((address_space(1))) void*)(base + voff0 + p * 8 * CC + c0),
                (__attribute__((address_space(3))) void*)(LDSARR + w * 4096 + p * 512),
                16, 0, 0);
        __syncthreads();
        if (active) {
            #pragma unroll
            for (int ks = 0; ks < 2; ks++) {
                int xo = (((ks * 4 + q) ^ s7) << 3);
                half8 af0 = *(const half8*)&LDSARR[abase + xo];
                half8 af1 = *(const half8*)&LDSARR[abase + 1024 + xo];
                half8 bf[8];
                #pragma unroll
                for (int jt = 0; jt < 8; jt++)
                    bf[jt] = *(const half8*)&LDSARR[bbase + jt * 1024 + xo];
                #pragma unroll
                for (int jt = 0; jt < 8; jt++) {
                    acc[0][jt] = __builtin_amdgcn_mfma_f32_16x16x32_f16(af0, bf[jt], acc[0][jt], 0, 0, 0);
                    acc[1][jt] = __builtin_amdgcn_mfma_f32_16x16x32_f16(af1, bf[jt], acc[1][jt], 0, 0, 0);
                }
            }
        }
        __syncthreads();
    }

    if (!active) return;   // after last barrier; epilogue is wave-local (shfl within wave)

    // epilogue: column norm (B packed unnormalized); fold 8 jt into <=2 class keys per (i,r),
    // dual-key butterfly, atomicMax. Compact state: invv[8] + key low-words lw[8] + 2 bitmasks.
    int wbase = cblk * 128;               // all 4 waves share the col window
    int clsLo = wbase / 196;
    float invv[8]; unsigned int lw[8]; int vbits = 0, lobits = 0;
    #pragma unroll
    for (int jt = 0; jt < 8; jt++) {
        int c = wbase + jt * 16 + l15;
        int cls = c / 196;
        int ms = c - cls * 196;
        lw[jt] = 0xFFFFFFFFu - (unsigned int)ms;
        if (cls == clsLo) lobits |= (1 << jt);
        int vld = (c < NREAL);
        if (vld) vbits |= (1 << jt);
        invv[jt] = vld ? (1.0f / fmaxf(sqrtf(nrms[b * NREAL + c]), 1e-8f)) : 0.f;
    }
    #pragma unroll
    for (int i = 0; i < 2; i++) {
        #pragma unroll
        for (int r = 0; r < 4; r++) {
            unsigned long long keyLo = 0ULL, keyHi = 0ULL;
            #pragma unroll
            for (int jt = 0; jt < 8; jt++) {
                float v = acc[i][jt][r] * invv[jt];
                unsigned int ub = __float_as_uint(v);
                unsigned int su = (ub & 0x80000000u) ? ~ub : (ub | 0x80000000u);
                unsigned long long key = ((vbits >> jt) & 1)
                    ? (((unsigned long long)su << 32) | (unsigned long long)lw[jt])
                    : 0ULL;
                if ((lobits >> jt) & 1) keyLo = (key > keyLo) ? key : keyLo;
                else                    keyHi = (key > keyHi) ? key : keyHi;
            }
            #pragma unroll
            for (int sft = 1; sft < 16; sft <<= 1) {
                unsigned long long oL = __shfl_xor(keyLo, sft, 64);
                unsigned long long oH = __shfl_xor(keyHi, sft, 64);
                if (oL > keyLo) keyLo = oL;
                if (oH > keyHi) keyHi = oH;
            }
            if (l15 == 0) {
                int gm = mblk * 128 + w * 32 + i * 16 + q * 4 + r;
                if (gm < MM) {
                    if (keyLo)
                        atomicMax(&gstat[((size_t)bq * NWAY + clsLo) * MP + gm], keyLo);
                    int clsHi = clsLo + 1;
                    if (keyHi && clsHi < NWAY)
                        atomicMax(&gstat[((size_t)bq * NWAY + clsHi) * MP + gm], keyHi);
                }
            }
        }
    }
}

// ---------------- mutual-NN mask + predict + per-sample CE -> atomicAdd out ----------------
__global__ void k_post(const unsigned long long* __restrict__ gstat,
                       const float* __restrict__ nrmq,
                       float* __restrict__ out, const int* __restrict__ qy) {
    int bq = blockIdx.x;
    int t = threadIdx.x;
    __shared__ float invq_s[MM];
    __shared__ float cm[NWAY * MM];
    __shared__ int   ca[NWAY * MM];
    __shared__ float gmax[MM];
    __shared__ int   jst[MM];
    __shared__ int   msk[MM];
    __shared__ float pred[NWAY];

    if (t < MM) invq_s[t] = 1.0f / fmaxf(sqrtf(nrmq[bq * MM + t]), 1e-8f);
    __syncthreads();

    for (int i = t; i < NWAY * MM; i += 256) {
        int n = i / MM, m = i - n * MM;
        unsigned long long key = gstat[((size_t)bq * NWAY + n) * MP + m];
        unsigned int hi = (unsigned int)(key >> 32);
        unsigned int bits = (hi & 0x80000000u) ? (hi ^ 0x80000000u) : ~hi;
        cm[i] = __uint_as_float(bits) * invq_s[m];
        ca[i] = (int)(0xFFFFFFFFu - (unsigned int)(key & 0xFFFFFFFFu));
    }
    __syncthreads();

    if (t < MM) {       // cross-class combine: ascending n, strict > == n-major first-index
        float bv = cm[t];
        int bj = ca[t];
        for (int n = 1; n < NWAY; n++) {
            float v = cm[n * MM + t];
            if (v > bv) { bv = v; bj = n * MM + ca[n * MM + t]; }
        }
        gmax[t] = bv; jst[t] = bj;
    }
    __syncthreads();

    if (t < MM) {       // mutual-NN: winner of my support-column group (max gmax, min index)
        int myj = jst[t];
        float myv = gmax[t];
        int lose = 0;
        for (int m2 = 0; m2 < MM; m2++) {
            if (jst[m2] == myj &&
                (gmax[m2] > myv || (gmax[m2] == myv && m2 < t))) lose = 1;
        }
        msk[t] = !lose;
    }
    __syncthreads();

    if (t < NWAY) {
        float p = 0.f;
        for (int m = 0; m < MM; m++) if (msk[m]) p += cm[t * MM + m];
        pred[t] = 2.0f * p;   // TEMPERATURE = 2
    }
    __syncthreads();

    if (t == 0) {
        float pm = pred[0];
        for (int n = 1; n < NWAY; n++) pm = fmaxf(pm, pred[n]);
        float s = 0.f;
        for (int n = 0; n < NWAY; n++) s += expf(pred[n] - pm);
        float lse = pm + logf(s);
        int y = qy[bq];
        atomicAdd(out, (lse - pred[y]) * (1.0f / (BB * QQ)));
    }
}

extern "C" void kernel_launch(void* const* d_in, const int* in_sizes, int n_in,
                              void* d_out, int out_size, void* d_ws, size_t ws_size,
                              hipStream_t stream) {
    const float* sx = (const float*)d_in[0];
    const float* qx = (const float*)d_in[2];
    const int*   qy = (const int*)d_in[3];
    float* out = (float*)d_out;
    float* ws  = (float*)d_ws;

    _Float16* Bpk = (_Float16*)(ws + BPK_OFF);
    _Float16* Apk = (_Float16*)(ws + APK_OFF);
    unsigned long long* gstat = (unsigned long long*)(ws + GSTAT_OFF);
    float* nrms = ws + NRMS_OFF;
    float* nrmq = ws + NRMQ_OFF;

    // zero gstat + nrms + nrmq (contiguous) and the output accumulator
    hipMemsetAsync(gstat, 0, (size_t)(2 * GSTAT_N + NRMS_SZ + NRMQ_SZ) * 4, stream);
    hipMemsetAsync(out, 0, 4, stream);
    hipLaunchKernelGGL(k_prep, dim3(3200), dim3(256), 0, stream, sx, qx, Apk, Bpk, nrmq, nrms);
    hipLaunchKernelGGL(k_sim,  dim3(8 * 38 * 16), dim3(256), 0, stream, Apk, Bpk, nrms, gstat);
    hipLaunchKernelGGL(k_post, dim3(300), dim3(256), 0, stream, gstat, nrmq, out, qy);
}

// Round 7
// 432.219 us; speedup vs baseline: 1.0723x; 1.0063x over previous
//
#include <hip/hip_runtime.h>
#include <math.h>

#define NWAY 5
#define KSHOT 5
#define BB 4
#define QQ 75
#define CC 640
#define MM 196
#define BQ (BB*QQ)          // 300
#define MP 208              // packed A rows per bq
#define NCOL 1024           // padded flat col space (980 real)
#define NREAL 980

// ---- ws layout (float offsets) ----
#define BPK_OFF   0
#define BPK_SZF   (BB*NCOL*CC/2)            // 1,310,720 (fp16 region)
#define APK_OFF   (BPK_OFF + BPK_SZF)
#define APK_SZF   ((BQ*MP + 64)*CC/2)       // +64 pad rows so mblk=1 OOB stays in-region
#define GSTAT_OFF (APK_OFF + APK_SZF)       // even -> 8B aligned
#define GSTAT_N   (BQ*NWAY*MP)              // 312,000 u64
#define NRMS_OFF  (GSTAT_OFF + 2*GSTAT_N)
#define NRMS_SZ   (BB*NWAY*MM)              // 3,920
#define NRMQ_OFF  (NRMS_OFF + NRMS_SZ)
#define NRMQ_SZ   (BQ*MM)                   // 58,800

typedef __attribute__((ext_vector_type(8))) _Float16 half8;
typedef __attribute__((ext_vector_type(4))) float floatx4;

// ---------------- fused prep: A-pack (3000 blocks) + B mean-pack (200 blocks) ----------------
// round-0 verified structure + G13: global reads vectorized to float4 (196 = 4*49, so a
// float4 never crosses a row; base offsets are multiples of 4 floats = 16B aligned).
__global__ void k_prep(const float* __restrict__ sx, const float* __restrict__ qx,
                       _Float16* __restrict__ Apk, _Float16* __restrict__ Bpk,
                       float* __restrict__ nrmq, float* __restrict__ nrms) {
    __shared__ float T[64 * 197];         // 50,432 B
    int t = threadIdx.x;
    int blk = blockIdx.x;
    if (blk < 3000) {
        // ---- query pack: Apk[bq][m][c] fp16 (unnormalized) + nrmq partials ----
        int bq = blk / 10, cc = blk % 10;
        int c0 = cc * 64;
        const float4* Q4 = (const float4*)(qx + (size_t)bq * CC * MM + (size_t)c0 * MM);
        for (int i4 = t; i4 < 16 * MM; i4 += 256) {   // 64*196/4 = 3136 float4s
            float4 v = Q4[i4];
            int base = i4 * 4;
            int ci = base / MM, m = base - ci * MM;   // m multiple of 4, no row-cross
            T[ci * 197 + m + 0] = v.x;
            T[ci * 197 + m + 1] = v.y;
            T[ci * 197 + m + 2] = v.z;
            T[ci * 197 + m + 3] = v.w;
        }
        __syncthreads();
        _Float16* out = Apk + (size_t)bq * MP * CC;
        int mloc = t >> 3, cj8 = t & 7;
        #pragma unroll
        for (int r = 0; r < 7; r++) {
            int mm = r * 32 + mloc;
            if (mm < MP) {
                half8 v;
                #pragma unroll
                for (int k = 0; k < 8; k++) {
                    float f = (mm < MM) ? T[(cj8 * 8 + k) * 197 + mm] : 0.f;
                    v[k] = (_Float16)f;
                }
                *(half8*)&out[(size_t)mm * CC + c0 + cj8 * 8] = v;
            }
        }
        if (t < MM) {
            float ss = 0.f;
            for (int ci = 0; ci < 64; ci++) { float v = T[ci * 197 + t]; ss += v * v; }
            atomicAdd(&nrmq[bq * MM + t], ss);
        }
    } else {
        // ---- support k-shot mean + pack: Bpk[b][col=n*196+ms][c] fp16 (unnorm) + nrms ----
        int bb = blk - 3000;
        int bn = bb / 10, cc = bb % 10;
        int b = bn / NWAY, n = bn % NWAY;
        int c0 = cc * 64;
        const float4* S4 = (const float4*)(sx + (size_t)bn * KSHOT * CC * MM + (size_t)c0 * MM);
        const int shot4 = CC * MM / 4;                // float4 stride per shot
        for (int i4 = t; i4 < 16 * MM; i4 += 256) {
            float sx_ = 0.f, sy = 0.f, sz = 0.f, sw = 0.f;
            #pragma unroll
            for (int k = 0; k < KSHOT; k++) {
                float4 v = S4[(size_t)k * shot4 + i4];
                sx_ += v.x; sy += v.y; sz += v.z; sw += v.w;
            }
            int base = i4 * 4;
            int ci = base / MM, m = base - ci * MM;
            T[ci * 197 + m + 0] = sx_ * 0.2f;
            T[ci * 197 + m + 1] = sy  * 0.2f;
            T[ci * 197 + m + 2] = sz  * 0.2f;
            T[ci * 197 + m + 3] = sw  * 0.2f;
        }
        __syncthreads();
        _Float16* out = Bpk + ((size_t)b * NCOL + (size_t)n * MM) * CC;
        int mloc = t >> 3, cj8 = t & 7;
        #pragma unroll
        for (int r = 0; r < 7; r++) {
            int mm = r * 32 + mloc;
            if (mm < MM) {
                half8 v;
                #pragma unroll
                for (int k = 0; k < 8; k++)
                    v[k] = (_Float16)T[(cj8 * 8 + k) * 197 + mm];
                *(half8*)&out[(size_t)mm * CC + c0 + cj8 * 8] = v;
            }
        }
        if (t < MM) {
            float ss = 0.f;
            for (int ci = 0; ci < 64; ci++) { float v = T[ci * 197 + t]; ss += v * v; }
            atomicAdd(&nrms[bn * MM + t], ss);
        }
    }
}

// ---------------- MFMA similarity v6: v5 (register diet, 4 blk/CU) + pad-tile trims ----------------
// 719 TF effective = ~80% of the plain-HIP 2-barrier structural ceiling at this shape;
// remaining lever is work-trimming:
//   active=false : (mblk1, w3)      rows 224-255 all pad  (round-4 trim, verified)
//   act1  =false : (mblk1, w2, i=1) rows 208-223 all pad  (new; wave-uniform guard,
//                  acc indices stay static -- rule #20 respected)
__global__ __launch_bounds__(256, 4) void k_sim(
    const _Float16* __restrict__ Apk, const _Float16* __restrict__ Bpk,
    const float* __restrict__ nrms, unsigned long long* __restrict__ gstat)
{
    __shared__ __align__(16) _Float16 Lds[16384];   // 32,768 B

    int id = blockIdx.x;
    int x = id & 7, s = id >> 3;          // XCD swizzle: 16 blocks of one bq -> same XCD
    int sub = s & 15, bqg = s >> 4;
    int bq = x + (bqg << 3);
    if (bq >= BQ) return;
    int mblk = sub >> 3, cblk = sub & 7;
    int b = bq / QQ;

    int t = threadIdx.x, lane = t & 63, w = t >> 6;
    int q = lane >> 4, l15 = lane & 15, s7 = l15 & 7;
    bool active = !(mblk == 1 && w == 3);           // wave-uniform
    bool act1   = active && !(mblk == 1 && w == 2); // i=1 sub-tile real?

    const _Float16* Ab = Apk + (size_t)bq * MP * CC + (size_t)(mblk * 128) * CC;
    const _Float16* Bb = Bpk + ((size_t)b * NCOL + (size_t)(cblk * 128)) * CC;
    const _Float16* base = (w < 2) ? Ab : Bb;     // waves 0,1 stage A; 2,3 stage B

    // single staging base offset (halfs); p-th load adds p*8*CC (compile-time)
    int rb = (w & 1) * 64 + (lane >> 3);
    int voff0 = rb * CC + (((lane & 7) ^ ((lane >> 3) & 7)) << 3);

    // fragment base addresses (halfs); per-ks xor offset added at use
    int abase = (w * 32 + l15) * 64;          // + i*1024
    int bbase = 8192 + l15 * 64;              // + jt*1024

    floatx4 acc[2][8];
    #pragma unroll
    for (int i = 0; i < 2; i++)
        #pragma unroll
        for (int j = 0; j < 8; j++) acc[i][j] = (floatx4){0.f, 0.f, 0.f, 0.f};

    for (int c0 = 0; c0 < CC; c0 += 64) {
        #pragma unroll
        for (int p = 0; p < 8; p++)
            __builtin_amdgcn_global_load_lds(
                (const __attribute__((address_space(1))) void*)(base + voff0 + p * 8 * CC + c0),
                (__attribute__((address_space(3))) void*)(Lds + w * 4096 + p * 512),
                16, 0, 0);
        __syncthreads();
        if (active) {
            #pragma unroll
            for (int ks = 0; ks < 2; ks++) {
                int xo = (((ks * 4 + q) ^ s7) << 3);
                half8 af0 = *(const half8*)&Lds[abase + xo];
                half8 bf[8];
                #pragma unroll
                for (int jt = 0; jt < 8; jt++)
                    bf[jt] = *(const half8*)&Lds[bbase + jt * 1024 + xo];
                #pragma unroll
                for (int jt = 0; jt < 8; jt++)
                    acc[0][jt] = __builtin_amdgcn_mfma_f32_16x16x32_f16(af0, bf[jt], acc[0][jt], 0, 0, 0);
                if (act1) {
                    half8 af1 = *(const half8*)&Lds[abase + 1024 + xo];
                    #pragma unroll
                    for (int jt = 0; jt < 8; jt++)
                        acc[1][jt] = __builtin_amdgcn_mfma_f32_16x16x32_f16(af1, bf[jt], acc[1][jt], 0, 0, 0);
                }
            }
        }
        __syncthreads();
    }

    if (!active) return;   // after last barrier; epilogue is wave-local (shfl within wave)

    // epilogue: column norm (B packed unnormalized); fold 8 jt into <=2 class keys per (i,r),
    // dual-key butterfly, atomicMax. Compact state: invv[8] + key low-words lw[8] + 2 bitmasks.
    int wbase = cblk * 128;               // all 4 waves share the col window
    int clsLo = wbase / 196;
    float invv[8]; unsigned int lw[8]; int vbits = 0, lobits = 0;
    #pragma unroll
    for (int jt = 0; jt < 8; jt++) {
        int c = wbase + jt * 16 + l15;
        int cls = c / 196;
        int ms = c - cls * 196;
        lw[jt] = 0xFFFFFFFFu - (unsigned int)ms;
        if (cls == clsLo) lobits |= (1 << jt);
        int vld = (c < NREAL);
        if (vld) vbits |= (1 << jt);
        invv[jt] = vld ? (1.0f / fmaxf(sqrtf(nrms[b * NREAL + c]), 1e-8f)) : 0.f;
    }
    #pragma unroll
    for (int i = 0; i < 2; i++) {
        if (i == 1 && !act1) continue;    // uniform guard; rows 208-223 are pad
        #pragma unroll
        for (int r = 0; r < 4; r++) {
            unsigned long long keyLo = 0ULL, keyHi = 0ULL;
            #pragma unroll
            for (int jt = 0; jt < 8; jt++) {
                float v = acc[i][jt][r] * invv[jt];
                unsigned int ub = __float_as_uint(v);
                unsigned int su = (ub & 0x80000000u) ? ~ub : (ub | 0x80000000u);
                unsigned long long key = ((vbits >> jt) & 1)
                    ? (((unsigned long long)su << 32) | (unsigned long long)lw[jt])
                    : 0ULL;
                if ((lobits >> jt) & 1) keyLo = (key > keyLo) ? key : keyLo;
                else                    keyHi = (key > keyHi) ? key : keyHi;
            }
            #pragma unroll
            for (int sft = 1; sft < 16; sft <<= 1) {
                unsigned long long oL = __shfl_xor(keyLo, sft, 64);
                unsigned long long oH = __shfl_xor(keyHi, sft, 64);
                if (oL > keyLo) keyLo = oL;
                if (oH > keyHi) keyHi = oH;
            }
            if (l15 == 0) {
                int gm = mblk * 128 + w * 32 + i * 16 + q * 4 + r;
                if (gm < MM) {
                    if (keyLo)
                        atomicMax(&gstat[((size_t)bq * NWAY + clsLo) * MP + gm], keyLo);
                    int clsHi = clsLo + 1;
                    if (keyHi && clsHi < NWAY)
                        atomicMax(&gstat[((size_t)bq * NWAY + clsHi) * MP + gm], keyHi);
                }
            }
        }
    }
}

// ---------------- mutual-NN mask + predict + per-sample CE -> atomicAdd out ----------------
__global__ void k_post(const unsigned long long* __restrict__ gstat,
                       const float* __restrict__ nrmq,
                       float* __restrict__ out, const int* __restrict__ qy) {
    int bq = blockIdx.x;
    int t = threadIdx.x;
    __shared__ float invq_s[MM];
    __shared__ float cm[NWAY * MM];
    __shared__ int   ca[NWAY * MM];
    __shared__ float gmax[MM];
    __shared__ int   jst[MM];
    __shared__ int   msk[MM];
    __shared__ float pred[NWAY];

    if (t < MM) invq_s[t] = 1.0f / fmaxf(sqrtf(nrmq[bq * MM + t]), 1e-8f);
    __syncthreads();

    for (int i = t; i < NWAY * MM; i += 256) {
        int n = i / MM, m = i - n * MM;
        unsigned long long key = gstat[((size_t)bq * NWAY + n) * MP + m];
        unsigned int hi = (unsigned int)(key >> 32);
        unsigned int bits = (hi & 0x80000000u) ? (hi ^ 0x80000000u) : ~hi;
        cm[i] = __uint_as_float(bits) * invq_s[m];
        ca[i] = (int)(0xFFFFFFFFu - (unsigned int)(key & 0xFFFFFFFFu));
    }
    __syncthreads();

    if (t < MM) {       // cross-class combine: ascending n, strict > == n-major first-index
        float bv = cm[t];
        int bj = ca[t];
        for (int n = 1; n < NWAY; n++) {
            float v = cm[n * MM + t];
            if (v > bv) { bv = v; bj = n * MM + ca[n * MM + t]; }
        }
        gmax[t] = bv; jst[t] = bj;
    }
    __syncthreads();

    if (t < MM) {       // mutual-NN: winner of my support-column group (max gmax, min index)
        int myj = jst[t];
        float myv = gmax[t];
        int lose = 0;
        for (int m2 = 0; m2 < MM; m2++) {
            if (jst[m2] == myj &&
                (gmax[m2] > myv || (gmax[m2] == myv && m2 < t))) lose = 1;
        }
        msk[t] = !lose;
    }
    __syncthreads();

    if (t < NWAY) {
        float p = 0.f;
        for (int m = 0; m < MM; m++) if (msk[m]) p += cm[t * MM + m];
        pred[t] = 2.0f * p;   // TEMPERATURE = 2
    }
    __syncthreads();

    if (t == 0) {
        float pm = pred[0];
        for (int n = 1; n < NWAY; n++) pm = fmaxf(pm, pred[n]);
        float s = 0.f;
        for (int n = 0; n < NWAY; n++) s += expf(pred[n] - pm);
        float lse = pm + logf(s);
        int y = qy[bq];
        atomicAdd(out, (lse - pred[y]) * (1.0f / (BB * QQ)));
    }
}

extern "C" void kernel_launch(void* const* d_in, const int* in_sizes, int n_in,
                              void* d_out, int out_size, void* d_ws, size_t ws_size,
                              hipStream_t stream) {
    const float* sx = (const float*)d_in[0];
    const float* qx = (const float*)d_in[2];
    const int*   qy = (const int*)d_in[3];
    float* out = (float*)d_out;
    float* ws  = (float*)d_ws;

    _Float16* Bpk = (_Float16*)(ws + BPK_OFF);
    _Float16* Apk = (_Float16*)(ws + APK_OFF);
    unsigned long long* gstat = (unsigned long long*)(ws + GSTAT_OFF);
    float* nrms = ws + NRMS_OFF;
    float* nrmq = ws + NRMQ_OFF;

    // zero gstat + nrms + nrmq (contiguous) and the output accumulator
    hipMemsetAsync(gstat, 0, (size_t)(2 * GSTAT_N + NRMS_SZ + NRMQ_SZ) * 4, stream);
    hipMemsetAsync(out, 0, 4, stream);
    hipLaunchKernelGGL(k_prep, dim3(3200), dim3(256), 0, stream, sx, qx, Apk, Bpk, nrmq, nrms);
    hipLaunchKernelGGL(k_sim,  dim3(8 * 38 * 16), dim3(256), 0, stream, Apk, Bpk, nrms, gstat);
    hipLaunchKernelGGL(k_post, dim3(300), dim3(256), 0, stream, gstat, nrmq, out, qy);
}